// Round 2
// 3116.368 us; speedup vs baseline: 1.3097x; 1.3097x over previous
//
#include <hip/hip_runtime.h>

#define TT 2048
#define HD 64

// LDS arena byte map (unchanged):
//   h1 : [0, 2048)      parity p, row r at (p*4+r)*256 B; 16B blocks XOR-swizzled
//   h2 : [2112, 4160)   same layout, +64B skew so h1+h2 chunk reads cover all 32 banks
//   fcs: [4160, 5184)
#define H1_BASE 0
#define H2_BASE 2112
#define FCS_BASE 4160

// Gate pre-scales folded into weights/biases at load time:
//   sigmoid gates (i,f,o): t = -log2(e)*z   -> sigma(z) = rcp(1+exp2(t))
//   tanh gate (g):         t = -2*log2(e)*z -> tanh(z)  = 2*rcp(1+exp2(t)) - 1
#define SIC -1.4426950408889634f
#define SGC -2.8853900817779268f

#if __has_builtin(__builtin_amdgcn_exp2f)
#define EXP2F(x) __builtin_amdgcn_exp2f(x)
#else
#define EXP2F(x) __expf(0.69314718055994531f * (x))
#endif
#if __has_builtin(__builtin_amdgcn_rcpf)
#define RCPF(x) __builtin_amdgcn_rcpf(x)
#else
#define RCPF(x) (1.0f / (x))
#endif

// v_exp_f32 + v_add + v_rcp_f32: no IEEE div sequence.
__device__ __forceinline__ float rcp1p(float t) { return RCPF(1.0f + EXP2F(t)); }

// 16B-block swizzle within a 256B row: block index b in [0,16) -> byte offset
__device__ __forceinline__ int swz(int b) { return ((b ^ ((b >> 2) & 3)) << 4); }

// pure DPP quad_perm move (bound_ctrl; all lanes active here).
// 0xB1 = quad_perm[1,0,3,2] (xor 1), 0x4E = quad_perm[2,3,0,1] (xor 2).
template<int CTRL>
__device__ __forceinline__ float dpp_get(float v) {
    return __int_as_float(__builtin_amdgcn_update_dpp(0, __float_as_int(v), CTRL, 0xF, 0xF, true));
}

__device__ __forceinline__ float4 scale4(float4 v, float s) {
    return make_float4(v.x * s, v.y * s, v.z * s, v.w * s);
}

#define DOT16(acc, W0, W1, W2, W3) \
    acc = __fmaf_rn(W0.x, hv0.x, acc); acc = __fmaf_rn(W0.y, hv0.y, acc); \
    acc = __fmaf_rn(W0.z, hv0.z, acc); acc = __fmaf_rn(W0.w, hv0.w, acc); \
    acc = __fmaf_rn(W1.x, hv1.x, acc); acc = __fmaf_rn(W1.y, hv1.y, acc); \
    acc = __fmaf_rn(W1.z, hv1.z, acc); acc = __fmaf_rn(W1.w, hv1.w, acc); \
    acc = __fmaf_rn(W2.x, hv2.x, acc); acc = __fmaf_rn(W2.y, hv2.y, acc); \
    acc = __fmaf_rn(W2.z, hv2.z, acc); acc = __fmaf_rn(W2.w, hv2.w, acc); \
    acc = __fmaf_rn(W3.x, hv3.x, acc); acc = __fmaf_rn(W3.y, hv3.y, acc); \
    acc = __fmaf_rn(W3.z, hv3.z, acc); acc = __fmaf_rn(W3.w, hv3.w, acc);

// seed accumulator from the first product (kills the 16 per-step init movs on L1)
#define DOT16I(acc, W0, W1, W2, W3) \
    acc = W0.x * hv0.x;                acc = __fmaf_rn(W0.y, hv0.y, acc); \
    acc = __fmaf_rn(W0.z, hv0.z, acc); acc = __fmaf_rn(W0.w, hv0.w, acc); \
    acc = __fmaf_rn(W1.x, hv1.x, acc); acc = __fmaf_rn(W1.y, hv1.y, acc); \
    acc = __fmaf_rn(W1.z, hv1.z, acc); acc = __fmaf_rn(W1.w, hv1.w, acc); \
    acc = __fmaf_rn(W2.x, hv2.x, acc); acc = __fmaf_rn(W2.y, hv2.y, acc); \
    acc = __fmaf_rn(W2.z, hv2.z, acc); acc = __fmaf_rn(W2.w, hv2.w, acc); \
    acc = __fmaf_rn(W3.x, hv3.x, acc); acc = __fmaf_rn(W3.y, hv3.y, acc); \
    acc = __fmaf_rn(W3.z, hv3.z, acc); acc = __fmaf_rn(W3.w, hv3.w, acc);

// P is a pointer-set prefix (pe/po); parity is baked into the pointers, so the
// whole read address is reg + compile-time immediate: zero per-step addressing.
#define ROWDOT(P, IMM, A0, A1, A2, A3) { \
    const float4 hv0 = *(const float4*)(P##0 + (IMM)); \
    const float4 hv1 = *(const float4*)(P##1 + (IMM)); \
    const float4 hv2 = *(const float4*)(P##2 + (IMM)); \
    const float4 hv3 = *(const float4*)(P##3 + (IMM)); \
    DOT16(A0, wA0, wA1, wA2, wA3); \
    DOT16(A1, wB0, wB1, wB2, wB3); \
    DOT16(A2, wC0, wC1, wC2, wC3); \
    DOT16(A3, wD0, wD1, wD2, wD3); }

// seeding variant: ALL FOUR accumulators start from their first product.
#define ROWDOTI(P, IMM, A0, A1, A2, A3) { \
    const float4 hv0 = *(const float4*)(P##0 + (IMM)); \
    const float4 hv1 = *(const float4*)(P##1 + (IMM)); \
    const float4 hv2 = *(const float4*)(P##2 + (IMM)); \
    const float4 hv3 = *(const float4*)(P##3 + (IMM)); \
    DOT16I(A0, wA0, wA1, wA2, wA3); \
    DOT16I(A1, wB0, wB1, wB2, wB3); \
    DOT16I(A2, wC0, wC1, wC2, wC3); \
    DOT16I(A3, wD0, wD1, wD2, wD3); }

// Packed row-select quad reduction: lane q (q = rk = lane&3 within the quad)
// ends with the full quad sum of row q's partials. 6 cndmask + 3 dpp-adds,
// replacing 16 BF2D + SEL4 of the old path.
#define QRED(e, r0, r1, r2, r3) \
    float e; { \
        float x_ = q1 ? (r1) : (r0); float y_ = q1 ? (r0) : (r1); \
        x_ += dpp_get<0xB1>(y_); \
        float z_ = q1 ? (r3) : (r2); float w_ = q1 ? (r2) : (r3); \
        z_ += dpp_get<0xB1>(w_); \
        float u_ = q2 ? z_ : x_; float v_ = q2 ? x_ : z_; \
        e = u_ + dpp_get<0x4E>(v_); \
    }

// One pipelined timestep. P = pointer set (pe even / po odd), X = x-register
// set (xa even / xb odd), L0WOFF/L1WOFF = parity write offsets (compile-time),
// DO_L1 = literal gate for L1's act/store (false only at i=0), XNI = prefetch idx.
#define STEP(P, X, L0WOFF, L1WOFF, DO_L1, XNI)                                  \
{                                                                               \
    float a00, a01, a02, a03, a10, a11, a12, a13;                               \
    float a20, a21, a22, a23, a30, a31, a32, a33;                               \
    if (isL0) {                                                                 \
        const float xv0 = X##0, xv1 = X##1, xv2 = X##2, xv3 = X##3;             \
        {                                                                       \
            const int xi_ = (XNI) < TT ? (XNI) : (TT - 1);                      \
            X##0 = xp0[xi_]; X##1 = xp1[xi_];                                   \
            X##2 = xp2[xi_]; X##3 = xp3[xi_];                                   \
        }                                                                       \
        a00 = __fmaf_rn(xv0, wxm0, bgm0); a01 = __fmaf_rn(xv0, wxm1, bgm1);     \
        a02 = __fmaf_rn(xv0, wxm2, bgm2); a03 = __fmaf_rn(xv0, wxm3, bgm3);     \
        a10 = __fmaf_rn(xv1, wxm0, bgm0); a11 = __fmaf_rn(xv1, wxm1, bgm1);     \
        a12 = __fmaf_rn(xv1, wxm2, bgm2); a13 = __fmaf_rn(xv1, wxm3, bgm3);     \
        a20 = __fmaf_rn(xv2, wxm0, bgm0); a21 = __fmaf_rn(xv2, wxm1, bgm1);     \
        a22 = __fmaf_rn(xv2, wxm2, bgm2); a23 = __fmaf_rn(xv2, wxm3, bgm3);     \
        a30 = __fmaf_rn(xv3, wxm0, bgm0); a31 = __fmaf_rn(xv3, wxm1, bgm1);     \
        a32 = __fmaf_rn(xv3, wxm2, bgm2); a33 = __fmaf_rn(xv3, wxm3, bgm3);     \
        ROWDOT(P, 0 * 256, a00, a01, a02, a03)                                  \
        ROWDOT(P, 1 * 256, a10, a11, a12, a13)                                  \
        ROWDOT(P, 2 * 256, a20, a21, a22, a23)                                  \
        ROWDOT(P, 3 * 256, a30, a31, a32, a33)                                  \
    } else {                                                                    \
        ROWDOTI(P, 0 * 256, a00, a01, a02, a03)                                 \
        ROWDOTI(P, 1 * 256, a10, a11, a12, a13)                                 \
        ROWDOTI(P, 2 * 256, a20, a21, a22, a23)                                 \
        ROWDOTI(P, 3 * 256, a30, a31, a32, a33)                                 \
    }                                                                           \
    QRED(e0_, a00, a10, a20, a30)                                               \
    QRED(e1_, a01, a11, a21, a31)                                               \
    QRED(e2_, a02, a12, a22, a32)                                               \
    QRED(e3_, a03, a13, a23, a33)                                               \
    if (isL0) {                                                                 \
        const float iv = rcp1p(e0_);                                            \
        const float fv = rcp1p(e1_);                                            \
        const float gv = __fmaf_rn(2.f, rcp1p(e2_), -1.f);                      \
        const float ov = rcp1p(e3_);                                            \
        cc = __fmaf_rn(fv, cc, iv * gv);                                        \
        const float th = __fmaf_rn(2.f, rcp1p(cc * SGC), -1.f);                 \
        *(float*)(wraddr + (L0WOFF)) = ov * th;                                 \
    } else {                                                                    \
        e0_ += __shfl_xor(e0_, 4, 64);                                          \
        e1_ += __shfl_xor(e1_, 4, 64);                                          \
        e2_ += __shfl_xor(e2_, 4, 64);                                          \
        e3_ += __shfl_xor(e3_, 4, 64);                                          \
        if ((DO_L1) && ck < 4) {                                                \
            const float iv = rcp1p(e0_ + bgm0);                                 \
            const float fv = rcp1p(e1_ + bgm1);                                 \
            const float gv = __fmaf_rn(2.f, rcp1p(e2_ + bgm2), -1.f);           \
            const float ov = rcp1p(e3_ + bgm3);                                 \
            cc = __fmaf_rn(fv, cc, iv * gv);                                    \
            hlast = ov * __fmaf_rn(2.f, rcp1p(cc * SGC), -1.f);                 \
            *(float*)(wraddr + (L1WOFF)) = hlast;                               \
        }                                                                       \
    }                                                                           \
    __syncthreads();                                                            \
}

// Block = 768 threads, 4 batch rows per block.
//   waves 0-3  (tid 0..255):   layer0.  j=tid>>2 (unit), ck=tid&3  (16-wide K chunk of 64)
//   waves 4-11 (tid 256..767): layer1.  p=tid-256, j=p>>3, ck=p&7 (16-wide chunk of K=128=[h1|h2])
// Pipeline: iter i does layer0 step i and layer1 step i-1; ONE barrier per iter.
// Loop is 2x-unrolled with parity-specialized bodies (i=0,1 peeled; i=2048 tail).
__global__ __launch_bounds__(768, 3)
void lstm2_kernel(const float* __restrict__ x,
                  const float* __restrict__ Wih0,
                  const float* __restrict__ Whh0,
                  const float* __restrict__ bih0,
                  const float* __restrict__ bhh0,
                  const float* __restrict__ Wih1,
                  const float* __restrict__ Whh1,
                  const float* __restrict__ bih1,
                  const float* __restrict__ bhh1,
                  const float* __restrict__ fcW,
                  const float* __restrict__ fcb,
                  float* __restrict__ out)
{
    __shared__ __align__(16) float arena_f[1296];
    char* const arena = (char*)arena_f;

    const int tid  = threadIdx.x;
    const int row0 = blockIdx.x * 4;

    const bool isL0 = (tid < 256);
    const int  p    = isL0 ? tid : (tid - 256);
    const int  j    = isL0 ? (p >> 2) : (p >> 3);
    const int  ck   = isL0 ? (p & 3)  : (p & 7);
    const int  ckk  = (ck < 4) ? ck : (ck - 4);
    const int  rk   = ck & 3;                      // this lane's output row
    const bool q1   = (rk & 1) != 0;
    const bool q2   = (rk & 2) != 0;

    // ---- weights: 16 explicit float4 registers, gate-prescaled at load ----
    const float* Wsrc;
    if (isL0)        Wsrc = Whh0;
    else if (ck < 4) Wsrc = Wih1;
    else             Wsrc = Whh1;
    const int kbase = 16 * ckk;
    const float4* W0p = (const float4*)(Wsrc + (0 * HD + j) * HD + kbase);
    const float4* W1p = (const float4*)(Wsrc + (1 * HD + j) * HD + kbase);
    const float4* W2p = (const float4*)(Wsrc + (2 * HD + j) * HD + kbase);
    const float4* W3p = (const float4*)(Wsrc + (3 * HD + j) * HD + kbase);
    const float4 wA0 = scale4(W0p[0], SIC), wA1 = scale4(W0p[1], SIC),
                 wA2 = scale4(W0p[2], SIC), wA3 = scale4(W0p[3], SIC);
    const float4 wB0 = scale4(W1p[0], SIC), wB1 = scale4(W1p[1], SIC),
                 wB2 = scale4(W1p[2], SIC), wB3 = scale4(W1p[3], SIC);
    const float4 wC0 = scale4(W2p[0], SGC), wC1 = scale4(W2p[1], SGC),
                 wC2 = scale4(W2p[2], SGC), wC3 = scale4(W2p[3], SGC);
    const float4 wD0 = scale4(W3p[0], SIC), wD1 = scale4(W3p[1], SIC),
                 wD2 = scale4(W3p[2], SIC), wD3 = scale4(W3p[3], SIC);

    // L0: masked (chunk 0 injects), pre-scaled bias + x-weight, used at acc init.
    // L1: unmasked pre-scaled bias, added post-reduction (after the xor-4 merge).
    float bgm0, bgm1, bgm2, bgm3, wxm0 = 0.f, wxm1 = 0.f, wxm2 = 0.f, wxm3 = 0.f;
    if (isL0) {
        const bool cz = (ck == 0);
        bgm0 = cz ? (bih0[0*HD+j] + bhh0[0*HD+j]) * SIC : 0.f;
        bgm1 = cz ? (bih0[1*HD+j] + bhh0[1*HD+j]) * SIC : 0.f;
        bgm2 = cz ? (bih0[2*HD+j] + bhh0[2*HD+j]) * SGC : 0.f;
        bgm3 = cz ? (bih0[3*HD+j] + bhh0[3*HD+j]) * SIC : 0.f;
        wxm0 = cz ? Wih0[0*HD+j] * SIC : 0.f;
        wxm1 = cz ? Wih0[1*HD+j] * SIC : 0.f;
        wxm2 = cz ? Wih0[2*HD+j] * SGC : 0.f;
        wxm3 = cz ? Wih0[3*HD+j] * SIC : 0.f;
    } else {
        bgm0 = (bih1[0*HD+j] + bhh1[0*HD+j]) * SIC;
        bgm1 = (bih1[1*HD+j] + bhh1[1*HD+j]) * SIC;
        bgm2 = (bih1[2*HD+j] + bhh1[2*HD+j]) * SGC;
        bgm3 = (bih1[3*HD+j] + bhh1[3*HD+j]) * SIC;
    }

    // per-thread LDS read constants; parity baked into TWO pointer sets so the
    // unrolled bodies use pure immediate offsets.
    const int o0 = swz(4 * ckk + 0);
    const int o1 = swz(4 * ckk + 1);
    const int o2 = swz(4 * ckk + 2);
    const int o3 = swz(4 * ckk + 3);
    const int rdBase = (ck < 4) ? H1_BASE : H2_BASE;   // isL0 has ck<4
    const int rdPh   = (ck < 4) ? 1 : 0;               // h1 readers: (i+1)&1; h2: i&1

    const char* pe0 = arena + rdBase + (rdPh << 10) + o0;         // even-i bodies
    const char* pe1 = arena + rdBase + (rdPh << 10) + o1;
    const char* pe2 = arena + rdBase + (rdPh << 10) + o2;
    const char* pe3 = arena + rdBase + (rdPh << 10) + o3;
    const char* po0 = arena + rdBase + ((rdPh ^ 1) << 10) + o0;   // odd-i bodies
    const char* po1 = arena + rdBase + ((rdPh ^ 1) << 10) + o1;
    const char* po2 = arena + rdBase + ((rdPh ^ 1) << 10) + o2;
    const char* po3 = arena + rdBase + ((rdPh ^ 1) << 10) + o3;

    char* const wraddr = arena + (isL0 ? H1_BASE : H2_BASE)
                       + ((ck & 3) << 8) + swz(j >> 2) + ((j & 3) << 2);

    // zero both parities of h1 and h2 (swizzle is a bijection -> linear zero OK)
    for (int z = tid; z < 512; z += 768) {
        *(float*)(arena + H1_BASE + 4 * z) = 0.f;
        *(float*)(arena + H2_BASE + 4 * z) = 0.f;
    }

    const float* xp0 = x + (row0 + 0) * TT;
    const float* xp1 = x + (row0 + 1) * TT;
    const float* xp2 = x + (row0 + 2) * TT;
    const float* xp3 = x + (row0 + 3) * TT;
    float xa0 = 0.f, xa1 = 0.f, xa2 = 0.f, xa3 = 0.f;   // even-step x
    float xb0 = 0.f, xb1 = 0.f, xb2 = 0.f, xb3 = 0.f;   // odd-step x
    if (isL0) {
        xa0 = xp0[0]; xa1 = xp1[0]; xa2 = xp2[0]; xa3 = xp3[0];
        xb0 = xp0[1]; xb1 = xp1[1]; xb2 = xp2[1]; xb3 = xp3[1];
    }

    const float fcwj = fcW[j];
    float cc = 0.f, hlast = 0.f;

    __syncthreads();

    STEP(pe, xa, 0, 1024, false, 2)      // i = 0: L0 only
    STEP(po, xb, 1024, 0, true, 3)       // i = 1: first L1 step (step 0)
#pragma unroll 1
    for (int i = 2; i < TT; i += 2) {
        STEP(pe, xa, 0, 1024, true, i + 2)
        STEP(po, xb, 1024, 0, true, i + 3)
    }
    // tail i = 2048: layer1 step 2047 only (no L0, no h2 store needed)
    if (!isL0) {
        float a00, a01, a02, a03, a10, a11, a12, a13;
        float a20, a21, a22, a23, a30, a31, a32, a33;
        ROWDOTI(pe, 0 * 256, a00, a01, a02, a03)
        ROWDOTI(pe, 1 * 256, a10, a11, a12, a13)
        ROWDOTI(pe, 2 * 256, a20, a21, a22, a23)
        ROWDOTI(pe, 3 * 256, a30, a31, a32, a33)
        QRED(e0_, a00, a10, a20, a30)
        QRED(e1_, a01, a11, a21, a31)
        QRED(e2_, a02, a12, a22, a32)
        QRED(e3_, a03, a13, a23, a33)
        e0_ += __shfl_xor(e0_, 4, 64);
        e1_ += __shfl_xor(e1_, 4, 64);
        e2_ += __shfl_xor(e2_, 4, 64);
        e3_ += __shfl_xor(e3_, 4, 64);
        if (ck < 4) {
            const float iv = rcp1p(e0_ + bgm0);
            const float fv = rcp1p(e1_ + bgm1);
            const float gv = __fmaf_rn(2.f, rcp1p(e2_ + bgm2), -1.f);
            const float ov = rcp1p(e3_ + bgm3);
            cc = __fmaf_rn(fv, cc, iv * gv);
            hlast = ov * __fmaf_rn(2.f, rcp1p(cc * SGC), -1.f);
        }
    }
    __syncthreads();

    // ---- FC: out[row] = sum_j h2[T-1][row][j] * fcW[j] + fcb ----
    if (!isL0 && ck < 4)
        *(float*)(arena + FCS_BASE + ((ck * HD + j) << 2)) = hlast * fcwj;
    __syncthreads();

    if (tid < 64) {
        const int r = tid >> 4, seg = tid & 15;
        const float4 v = ((const float4*)(arena + FCS_BASE))[r * 16 + seg];
        float s = (v.x + v.y) + (v.z + v.w);
        s += __shfl_xor(s, 1, 64);
        s += __shfl_xor(s, 2, 64);
        s += __shfl_xor(s, 4, 64);
        s += __shfl_xor(s, 8, 64);
        if (seg == 0) out[row0 + r] = s + fcb[0];
    }
}

extern "C" void kernel_launch(void* const* d_in, const int* in_sizes, int n_in,
                              void* d_out, int out_size, void* d_ws, size_t ws_size,
                              hipStream_t stream) {
    const float* x    = (const float*)d_in[0];
    const float* Wih0 = (const float*)d_in[1];
    const float* Whh0 = (const float*)d_in[2];
    const float* bih0 = (const float*)d_in[3];
    const float* bhh0 = (const float*)d_in[4];
    const float* bih1 = (const float*)d_in[7];
    const float* Wih1 = (const float*)d_in[5];
    const float* Whh1 = (const float*)d_in[6];
    const float* bhh1 = (const float*)d_in[8];
    const float* fcW  = (const float*)d_in[9];
    const float* fcb  = (const float*)d_in[10];
    float* out = (float*)d_out;

    lstm2_kernel<<<256, 768, 0, stream>>>(x, Wih0, Whh0, bih0, bhh0,
                                          Wih1, Whh1, bih1, bhh1,
                                          fcW, fcb, out);
}